// Round 12
// baseline (275.589 us; speedup 1.0000x reference)
//
#include <hip/hip_runtime.h>

#define EPSV 1e-5f

typedef __attribute__((ext_vector_type(8))) short short8;
typedef __attribute__((ext_vector_type(4))) float f32x4;
typedef unsigned int uint;
typedef unsigned short ushort;

// ---------------- init: cnt=0, + graph segment starts (block 0) --------------
__global__ __launch_bounds__(256) void init_k(int* __restrict__ cnt,
                                              const int* __restrict__ batch,
                                              int* __restrict__ gstart,
                                              int nnodes, int ngraphs) {
    int i = blockIdx.x * 256 + threadIdx.x;
    if (i < nnodes) cnt[i] = 0;
    if (blockIdx.x == 0 && threadIdx.x <= ngraphs) {
        int g = threadIdx.x;
        int lo = 0, hi = nnodes;
        while (lo < hi) {
            int mid = (lo + hi) >> 1;
            if (batch[mid] < g) lo = mid + 1; else hi = mid;
        }
        gstart[g] = lo;
    }
}

__global__ __launch_bounds__(256) void degcount_k(const int* __restrict__ dst,
                                                  int* __restrict__ cnt,
                                                  int nedges) {
    int i = blockIdx.x * 256 + threadIdx.x;
    if (i < nedges) atomicAdd(&cnt[dst[i]], 1);
}

// ---------------- exclusive scan of cnt[] -> rowptr[] (+ dinv) ---------------
__global__ __launch_bounds__(256) void scan1_k(const int* __restrict__ cnt,
                                               int* __restrict__ rowptr,
                                               int* __restrict__ bsum,
                                               float* __restrict__ dinv, int n) {
    __shared__ int sh[256];
    const int tx = threadIdx.x;
    const int base = blockIdx.x * 1024;
    int v[4];
    int s = 0;
#pragma unroll
    for (int j = 0; j < 4; j++) {
        int idx = base + tx * 4 + j;
        v[j] = (idx < n) ? cnt[idx] : 0;
        if (idx < n) dinv[idx] = rsqrtf(1.0f + (float)v[j]);
        s += v[j];
    }
    sh[tx] = s;
    __syncthreads();
#pragma unroll
    for (int off = 1; off < 256; off <<= 1) {
        int t = (tx >= off) ? sh[tx - off] : 0;
        __syncthreads();
        sh[tx] += t;
        __syncthreads();
    }
    int run = sh[tx] - s;
#pragma unroll
    for (int j = 0; j < 4; j++) {
        int idx = base + tx * 4 + j;
        if (idx < n) rowptr[idx] = run;
        run += v[j];
    }
    if (tx == 255) bsum[blockIdx.x] = sh[255];
}

__global__ __launch_bounds__(64) void scan2_k(int* __restrict__ bsum, int nb) {
    __shared__ int sh[64];
    const int tx = threadIdx.x;
    int v = (tx < nb) ? bsum[tx] : 0;
    sh[tx] = v;
    __syncthreads();
#pragma unroll
    for (int off = 1; off < 64; off <<= 1) {
        int t = (tx >= off) ? sh[tx - off] : 0;
        __syncthreads();
        sh[tx] += t;
        __syncthreads();
    }
    if (tx < nb) bsum[tx] = sh[tx] - v;
}

__global__ __launch_bounds__(256) void scan3_k(int* __restrict__ rowptr,
                                               int* __restrict__ cur,
                                               const int* __restrict__ bsum,
                                               int n, int nedges) {
    const int tx = threadIdx.x;
    const int base = blockIdx.x * 1024;
    int off = bsum[blockIdx.x];
#pragma unroll
    for (int j = 0; j < 4; j++) {
        int idx = base + tx * 4 + j;
        if (idx < n) {
            int r = rowptr[idx] + off;
            rowptr[idx] = r;
            cur[idx] = r;
        }
    }
    if (blockIdx.x == 0 && tx == 0) rowptr[n] = nedges;
}

__global__ __launch_bounds__(256) void fill_k(const int* __restrict__ src,
                                              const int* __restrict__ dst,
                                              int* __restrict__ cur,
                                              int* __restrict__ esrc, int nedges) {
    int i = blockIdx.x * 256 + threadIdx.x;
    if (i >= nedges) return;
    int pos = atomicAdd(&cur[dst[i]], 1);
    esrc[pos] = src[i];
}

// ---------------- W prep: transpose + bf16 RNE, both layers ------------------
__global__ __launch_bounds__(256) void wprep_k(const float* __restrict__ W1,
                                               const float* __restrict__ W2,
                                               ushort* __restrict__ wt1,
                                               ushort* __restrict__ wt2) {
    int i = blockIdx.x * 256 + threadIdx.x;
    if (i < 512 * 128) {
        int k = i >> 7, c = i & 127;
        unsigned u = __builtin_bit_cast(unsigned, W1[i]);
        wt1[c * 512 + k] = (ushort)((u + 0x7fffu + ((u >> 16) & 1u)) >> 16);
    } else if (i < 512 * 128 + 128 * 128) {
        int j = i - 512 * 128;
        int k = j >> 7, c = j & 127;
        unsigned u = __builtin_bit_cast(unsigned, W2[j]);
        wt2[c * 128 + k] = (ushort)((u + 0x7fffu + ((u >> 16) & 1u)) >> 16);
    }
}

// ---------------- MFMA GEMM: H = X @ W, + fused hb = bf16(H*dinv) -----------
// A split-bf16 (ah+al, exact), B pure bf16-RNE.
// W FULLY RESIDENT IN LDS (staged once, one barrier); K-loop is barrier-free:
// each wave streams its A rows with 2-deep prefetch, reads B via swizzled
// ds_read_b128, and issues MFMAs independently of other waves.
// 512 thr = 8 waves; wave = 16 rows (wu>>1) x 64 cols (wu&1).  BM = 64.
// LDS logical layout: [c 128][slot K/8 x 16B], phys slot = slot ^ (c&7)
// (2-way bank aliasing only, free per m136).
template <int K>
__global__ __launch_bounds__(512) void gemm_mfma_k(const float* __restrict__ X,
                                                   const ushort* __restrict__ wT,
                                                   const float* __restrict__ dinv,
                                                   float* __restrict__ H,
                                                   ushort* __restrict__ hb16,
                                                   int nrows) {
    __shared__ ushort wsm[128 * K];   // K=512: 128 KB, K=128: 32 KB

    const int tx = threadIdx.x;
    const int wu = __builtin_amdgcn_readfirstlane(tx >> 6);
    const int l = tx & 63;
    const int lrow = l & 15;
    const int kgrp = l >> 4;
    const int wrow = wu >> 1;         // 0..3: 16-row stripe
    const int wcol = wu & 1;          // 0..1: 64-col half
    const int row0 = blockIdx.x * 64 + wrow * 16;

    // ---- stage all of W once: K/32 x 1KB global_load_lds per wave ----
    constexpr int NPW = K / 32;       // instructions per wave
#pragma unroll
    for (int q = 0; q < NPW; q++) {
        int j = wu * NPW + q;                       // 1KB chunk id
        int byte0 = j * 1024 + l * 16;              // this lane's LDS byte
        int c = byte0 / (K * 2);
        int slot = (byte0 % (K * 2)) >> 4;
        const ushort* src = wT + (size_t)c * K + ((slot ^ (c & 7)) * 8);
        ushort* dst = &wsm[j * 512];                // +lane*16B by HW
        __builtin_amdgcn_global_load_lds(
            (const __attribute__((address_space(1))) unsigned int*)(const void*)src,
            (__attribute__((address_space(3))) unsigned int*)(void*)dst,
            16, 0, 0);
    }

    int arow = row0 + lrow;
    if (arow >= nrows) arow = nrows - 1;            // clamp (store guarded)
    const float* xrow = X + (size_t)arow * K + kgrp * 8;

    f32x4 acc[4];
#pragma unroll
    for (int g = 0; g < 4; g++) acc[g] = (f32x4){0.f, 0.f, 0.f, 0.f};

    constexpr int NIT = K / 64;

    // A prefetch for iters 0 and 1 (issued while staging is in flight)
    f32x4 c0 = *reinterpret_cast<const f32x4*>(xrow);
    f32x4 c1 = *reinterpret_cast<const f32x4*>(xrow + 4);
    f32x4 c2 = *reinterpret_cast<const f32x4*>(xrow + 32);
    f32x4 c3 = *reinterpret_cast<const f32x4*>(xrow + 36);
    f32x4 d0 = c0, d1 = c1, d2 = c2, d3 = c3;
    if (NIT > 1) {
        d0 = *reinterpret_cast<const f32x4*>(xrow + 64);
        d1 = *reinterpret_cast<const f32x4*>(xrow + 68);
        d2 = *reinterpret_cast<const f32x4*>(xrow + 96);
        d3 = *reinterpret_cast<const f32x4*>(xrow + 100);
    }

    __syncthreads();   // staging complete (compiler drains vmcnt before barrier)

#pragma unroll
    for (int i = 0; i < NIT; i++) {
        // A prefetch: iter i+2
        f32x4 e0 = d0, e1 = d1, e2 = d2, e3 = d3;
        if (i + 2 < NIT) {
            const float* nx = xrow + (i + 2) * 64;
            e0 = *reinterpret_cast<const f32x4*>(nx);
            e1 = *reinterpret_cast<const f32x4*>(nx + 4);
            e2 = *reinterpret_cast<const f32x4*>(nx + 32);
            e3 = *reinterpret_cast<const f32x4*>(nx + 36);
        }

#pragma unroll
        for (int sub = 0; sub < 2; sub++) {
            // A fragment: 8 contiguous f32 -> bf16 hi/lo (exact split)
            short8 ah, al;
#pragma unroll
            for (int j = 0; j < 8; j++) {
                float f = (sub == 0) ? ((j < 4) ? c0[j] : c1[j - 4])
                                     : ((j < 4) ? c2[j] : c3[j - 4]);
                unsigned u = __builtin_bit_cast(unsigned, f);
                ah[j] = (short)(u >> 16);
                float hif = __builtin_bit_cast(float, u & 0xffff0000u);
                float lof = f - hif;
                al[j] = (short)(__builtin_bit_cast(unsigned, lof) >> 16);
            }
            int slot = i * 8 + sub * 4 + kgrp;      // logical 16B slot in c-row
#pragma unroll
            for (int g = 0; g < 4; g++) {
                int cc = (wcol * 4 + g) * 16 + lrow;
                int phys = slot ^ (cc & 7);
                short8 bb = *reinterpret_cast<const short8*>(
                    &wsm[(size_t)cc * K + phys * 8]);
                acc[g] = __builtin_amdgcn_mfma_f32_16x16x32_bf16(ah, bb, acc[g], 0, 0, 0);
                acc[g] = __builtin_amdgcn_mfma_f32_16x16x32_bf16(al, bb, acc[g], 0, 0, 0);
            }
        }

        c0 = d0; c1 = d1; c2 = d2; c3 = d3;
        d0 = e0; d1 = e1; d2 = e2; d3 = e3;
    }

    // C: row = row0 + kgrp*4 + r, col = wcol*64 + g*16 + lrow (m89 mapping)
#pragma unroll
    for (int r = 0; r < 4; r++) {
        int row = row0 + kgrp * 4 + r;
        if (row < nrows) {
            float dn = dinv[row];
            float* hrow = H + (size_t)row * 128 + wcol * 64 + lrow;
            ushort* hbrow = hb16 + (size_t)row * 128 + wcol * 64 + lrow;
#pragma unroll
            for (int g = 0; g < 4; g++) {
                float v = acc[g][r];
                hrow[g * 16] = v;
                unsigned u = __builtin_bit_cast(unsigned, v * dn);
                hbrow[g * 16] = (ushort)((u + 0x7fffu + ((u >> 16) & 1u)) >> 16);
            }
        }
    }
}

// ------ fused aggregate: out[d] = dinv[d]*(h[d]*dinv[d] + sum hb[src]) -------
// then bias + BN(eval) + ReLU.  One 64-lane wave per node, 4 B/lane gathers.
__global__ __launch_bounds__(256) void agg_k(const float* __restrict__ H,
                                             const uint* __restrict__ hb,
                                             const int* __restrict__ rowptr,
                                             const int* __restrict__ esrc,
                                             const float* __restrict__ dinv,
                                             const float* __restrict__ bias,
                                             const float* __restrict__ gamma,
                                             const float* __restrict__ beta,
                                             const float* __restrict__ rm,
                                             const float* __restrict__ rv,
                                             float* __restrict__ OUT,
                                             int nnodes) {
    int node = blockIdx.x * 4 + (threadIdx.x >> 6);
    if (node >= nnodes) return;
    node = __builtin_amdgcn_readfirstlane(node);
    const int l = threadIdx.x & 63;
    const int c = l * 2;
    const float dn = dinv[node];
    const int beg = rowptr[node], end = rowptr[node + 1];

    float2 hv = *reinterpret_cast<const float2*>(H + (size_t)node * 128 + c);
    float ax0 = hv.x * dn, ay0 = hv.y * dn;
    float ax1 = 0.f, ay1 = 0.f, ax2 = 0.f, ay2 = 0.f, ax3 = 0.f, ay3 = 0.f;
    const uint* hbl = hb + l;

    int j = beg;
    for (; j + 3 < end; j += 4) {
        int s0 = esrc[j], s1 = esrc[j + 1], s2 = esrc[j + 2], s3 = esrc[j + 3];
        uint u0 = hbl[(size_t)s0 * 64];
        uint u1 = hbl[(size_t)s1 * 64];
        uint u2 = hbl[(size_t)s2 * 64];
        uint u3 = hbl[(size_t)s3 * 64];
        ax0 += __builtin_bit_cast(float, u0 << 16);
        ay0 += __builtin_bit_cast(float, u0 & 0xffff0000u);
        ax1 += __builtin_bit_cast(float, u1 << 16);
        ay1 += __builtin_bit_cast(float, u1 & 0xffff0000u);
        ax2 += __builtin_bit_cast(float, u2 << 16);
        ay2 += __builtin_bit_cast(float, u2 & 0xffff0000u);
        ax3 += __builtin_bit_cast(float, u3 << 16);
        ay3 += __builtin_bit_cast(float, u3 & 0xffff0000u);
    }
    for (; j < end; j++) {
        uint u0 = hbl[(size_t)esrc[j] * 64];
        ax0 += __builtin_bit_cast(float, u0 << 16);
        ay0 += __builtin_bit_cast(float, u0 & 0xffff0000u);
    }
    float accx = (ax0 + ax1) + (ax2 + ax3);
    float accy = (ay0 + ay1) + (ay2 + ay3);

    float v0 = accx * dn + bias[c];
    float v1 = accy * dn + bias[c + 1];
    v0 = (v0 - rm[c])     * rsqrtf(rv[c] + EPSV)     * gamma[c]     + beta[c];
    v1 = (v1 - rm[c + 1]) * rsqrtf(rv[c + 1] + EPSV) * gamma[c + 1] + beta[c + 1];
    v0 = fmaxf(v0, 0.0f);
    v1 = fmaxf(v1, 0.0f);

    *reinterpret_cast<float2*>(OUT + (size_t)node * 128 + c) = make_float2(v0, v1);
}

// ---------------- mean pool, stage 1: per-(graph, chunk) partial sums --------
__global__ __launch_bounds__(256) void pool1_k(const float* __restrict__ V,
                                               const int* __restrict__ gstart,
                                               float* __restrict__ partial) {
    __shared__ float sh[256];
    const int g = blockIdx.x >> 5;
    const int p = blockIdx.x & 31;
    const int tx = threadIdx.x;
    const int ch = tx & 127;
    const int sub = tx >> 7;
    const int beg = gstart[g], end = gstart[g + 1];
    const int chunk = (end - beg + 31) >> 5;
    const int s = beg + p * chunk;
    const int e = min(s + chunk, end);
    float acc = 0.0f;
    for (int i = s + sub; i < e; i += 2)
        acc += V[(size_t)i * 128 + ch];
    sh[tx] = acc;
    __syncthreads();
    if (tx < 128)
        partial[(size_t)blockIdx.x * 128 + tx] = sh[tx] + sh[tx + 128];
}

// ---------------- mean pool, stage 2 -----------------------------------------
__global__ __launch_bounds__(128) void pool2_k(const float* __restrict__ partial,
                                               const int* __restrict__ gstart,
                                               float* __restrict__ pooled) {
    const int g = blockIdx.x;
    const int ch = threadIdx.x;
    float s = 0.0f;
#pragma unroll
    for (int p = 0; p < 32; p++)
        s += partial[(size_t)((g << 5) + p) * 128 + ch];
    float cnt = fmaxf((float)(gstart[g + 1] - gstart[g]), 1.0f);
    pooled[g * 128 + ch] = s / cnt;
}

// ---------------- final: out[g][o] = pooled[g] @ Wl + bl ---------------------
__global__ __launch_bounds__(128) void final_k(const float* __restrict__ pooled,
                                               const float* __restrict__ Wl,
                                               const float* __restrict__ bl,
                                               float* __restrict__ out) {
    int tx = threadIdx.x;
    int g = tx >> 1, o = tx & 1;
    float s = 0.0f;
#pragma unroll 8
    for (int c = 0; c < 128; c++) s += pooled[g * 128 + c] * Wl[c * 2 + o];
    out[tx] = s + bl[o];
}

extern "C" void kernel_launch(void* const* d_in, const int* in_sizes, int n_in,
                              void* d_out, int out_size, void* d_ws, size_t ws_size,
                              hipStream_t stream) {
    const float* x      = (const float*)d_in[0];
    const int*   ei     = (const int*)d_in[1];
    const int*   batch  = (const int*)d_in[2];
    const float* W1     = (const float*)d_in[3];
    const float* b1     = (const float*)d_in[4];
    const float* gamma1 = (const float*)d_in[5];
    const float* beta1  = (const float*)d_in[6];
    const float* rm1    = (const float*)d_in[7];
    const float* rv1    = (const float*)d_in[8];
    const float* W2     = (const float*)d_in[9];
    const float* b2     = (const float*)d_in[10];
    const float* gamma2 = (const float*)d_in[11];
    const float* beta2  = (const float*)d_in[12];
    const float* rm2    = (const float*)d_in[13];
    const float* rv2    = (const float*)d_in[14];
    const float* Wl     = (const float*)d_in[15];
    const float* bl     = (const float*)d_in[16];
    float* out = (float*)d_out;

    const int nnodes  = in_sizes[2];
    const int nedges  = in_sizes[1] / 2;
    const int ngraphs = 64;
    const int* srcp = ei;
    const int* dstp = ei + nedges;

    float* wsA     = (float*)d_ws;                       // [nnodes*128]
    float* wsB     = wsA + (size_t)nnodes * 128;         // [nnodes*128]
    float* dinv    = wsB + (size_t)nnodes * 128;         // [nnodes]
    float* pooled  = dinv + nnodes;                      // [64*128]
    float* partial = pooled + 64 * 128;                  // [64*32*128]
    int*   cnt     = (int*)(partial + 64 * 32 * 128);    // [nnodes]
    int*   rowptr  = cnt + nnodes;                       // [nnodes+1]
    int*   cur     = rowptr + nnodes + 1;                // [nnodes]
    int*   bsum    = cur + nnodes;                       // [64]
    int*   gstart  = bsum + 64;                          // [65]
    int*   esrc    = gstart + 65;                        // [nedges]
    uintptr_t wp   = ((uintptr_t)(esrc + nedges) + 15) & ~(uintptr_t)15;
    ushort* wt1  = (ushort*)wp;                          // [128*512]
    ushort* wt2  = wt1 + 512 * 128;                      // [128*128]
    ushort* hb16 = wt2 + 128 * 128;                      // [nnodes*128] bf16
    uint*   hb   = (uint*)hb16;                          // same buffer, uint view

    dim3 blk(256);
    const int gNodes = (nnodes + 255) / 256;
    const int gEdges = (nedges + 255) / 256;
    const int gGemm  = (nnodes + 63) / 64;
    const int gAgg   = (nnodes + 3) / 4;
    const int nScanB = (nnodes + 1023) / 1024;

    // ---- graph preprocessing (CSR by dst + graph segments + W prep) ----
    init_k<<<gNodes, blk, 0, stream>>>(cnt, batch, gstart, nnodes, ngraphs);
    wprep_k<<<(512 * 128 + 128 * 128 + 255) / 256, blk, 0, stream>>>(W1, W2, wt1, wt2);
    degcount_k<<<gEdges, blk, 0, stream>>>(dstp, cnt, nedges);
    scan1_k<<<nScanB, blk, 0, stream>>>(cnt, rowptr, bsum, dinv, nnodes);
    scan2_k<<<1, 64, 0, stream>>>(bsum, nScanB);
    scan3_k<<<nScanB, blk, 0, stream>>>(rowptr, cur, bsum, nnodes, nedges);
    fill_k<<<gEdges, blk, 0, stream>>>(srcp, dstp, cur, esrc, nedges);

    // ---- layer 1: MFMA GEMM (+hb) + fused aggregate/BN/ReLU ----
    gemm_mfma_k<512><<<gGemm, dim3(512), 0, stream>>>(x, wt1, dinv, wsA, hb16, nnodes);
    agg_k<<<gAgg, blk, 0, stream>>>(wsA, hb, rowptr, esrc, dinv, b1, gamma1, beta1,
                                    rm1, rv1, wsB, nnodes);

    // ---- layer 2: MFMA GEMM (+hb) + fused aggregate/BN/ReLU ----
    gemm_mfma_k<128><<<gGemm, dim3(512), 0, stream>>>(wsB, wt2, dinv, wsA, hb16, nnodes);
    agg_k<<<gAgg, blk, 0, stream>>>(wsA, hb, rowptr, esrc, dinv, b2, gamma2, beta2,
                                    rm2, rv2, wsB, nnodes);

    // ---- readout ----
    pool1_k<<<ngraphs * 32, blk, 0, stream>>>(wsB, gstart, partial);
    pool2_k<<<ngraphs, 128, 0, stream>>>(partial, gstart, pooled);
    final_k<<<1, 128, 0, stream>>>(pooled, Wl, bl, out);
}

// Round 14
// 258.469 us; speedup vs baseline: 1.0662x; 1.0662x over previous
//
#include <hip/hip_runtime.h>

#define EPSV 1e-5f

typedef __attribute__((ext_vector_type(8))) short short8;
typedef __attribute__((ext_vector_type(4))) float f32x4;
typedef unsigned int uint;
typedef unsigned short ushort;

// ---------------- init: cnt=0, + graph segment starts (block 0) --------------
__global__ __launch_bounds__(256) void init_k(int* __restrict__ cnt,
                                              const int* __restrict__ batch,
                                              int* __restrict__ gstart,
                                              int nnodes, int ngraphs) {
    int i = blockIdx.x * 256 + threadIdx.x;
    if (i < nnodes) cnt[i] = 0;
    if (blockIdx.x == 0 && threadIdx.x <= ngraphs) {
        int g = threadIdx.x;
        int lo = 0, hi = nnodes;
        while (lo < hi) {
            int mid = (lo + hi) >> 1;
            if (batch[mid] < g) lo = mid + 1; else hi = mid;
        }
        gstart[g] = lo;
    }
}

__global__ __launch_bounds__(256) void degcount_k(const int* __restrict__ dst,
                                                  int* __restrict__ cnt,
                                                  int nedges) {
    int i = blockIdx.x * 256 + threadIdx.x;
    if (i < nedges) atomicAdd(&cnt[dst[i]], 1);
}

// ---------------- exclusive scan of cnt[] -> rowptr[] (+ dinv) ---------------
__global__ __launch_bounds__(256) void scan1_k(const int* __restrict__ cnt,
                                               int* __restrict__ rowptr,
                                               int* __restrict__ bsum,
                                               float* __restrict__ dinv, int n) {
    __shared__ int sh[256];
    const int tx = threadIdx.x;
    const int base = blockIdx.x * 1024;
    int v[4];
    int s = 0;
#pragma unroll
    for (int j = 0; j < 4; j++) {
        int idx = base + tx * 4 + j;
        v[j] = (idx < n) ? cnt[idx] : 0;
        if (idx < n) dinv[idx] = rsqrtf(1.0f + (float)v[j]);
        s += v[j];
    }
    sh[tx] = s;
    __syncthreads();
#pragma unroll
    for (int off = 1; off < 256; off <<= 1) {
        int t = (tx >= off) ? sh[tx - off] : 0;
        __syncthreads();
        sh[tx] += t;
        __syncthreads();
    }
    int run = sh[tx] - s;
#pragma unroll
    for (int j = 0; j < 4; j++) {
        int idx = base + tx * 4 + j;
        if (idx < n) rowptr[idx] = run;
        run += v[j];
    }
    if (tx == 255) bsum[blockIdx.x] = sh[255];
}

__global__ __launch_bounds__(64) void scan2_k(int* __restrict__ bsum, int nb) {
    __shared__ int sh[64];
    const int tx = threadIdx.x;
    int v = (tx < nb) ? bsum[tx] : 0;
    sh[tx] = v;
    __syncthreads();
#pragma unroll
    for (int off = 1; off < 64; off <<= 1) {
        int t = (tx >= off) ? sh[tx - off] : 0;
        __syncthreads();
        sh[tx] += t;
        __syncthreads();
    }
    if (tx < nb) bsum[tx] = sh[tx] - v;
}

__global__ __launch_bounds__(256) void scan3_k(int* __restrict__ rowptr,
                                               int* __restrict__ cur,
                                               const int* __restrict__ bsum,
                                               int n, int nedges) {
    const int tx = threadIdx.x;
    const int base = blockIdx.x * 1024;
    int off = bsum[blockIdx.x];
#pragma unroll
    for (int j = 0; j < 4; j++) {
        int idx = base + tx * 4 + j;
        if (idx < n) {
            int r = rowptr[idx] + off;
            rowptr[idx] = r;
            cur[idx] = r;
        }
    }
    if (blockIdx.x == 0 && tx == 0) rowptr[n] = nedges;
}

__global__ __launch_bounds__(256) void fill_k(const int* __restrict__ src,
                                              const int* __restrict__ dst,
                                              int* __restrict__ cur,
                                              int* __restrict__ esrc, int nedges) {
    int i = blockIdx.x * 256 + threadIdx.x;
    if (i >= nedges) return;
    int pos = atomicAdd(&cur[dst[i]], 1);
    esrc[pos] = src[i];
}

// ---------------- W prep: transpose + bf16 RNE, both layers ------------------
__global__ __launch_bounds__(256) void wprep_k(const float* __restrict__ W1,
                                               const float* __restrict__ W2,
                                               ushort* __restrict__ wt1,
                                               ushort* __restrict__ wt2) {
    int i = blockIdx.x * 256 + threadIdx.x;
    if (i < 512 * 128) {
        int k = i >> 7, c = i & 127;
        unsigned u = __builtin_bit_cast(unsigned, W1[i]);
        wt1[c * 512 + k] = (ushort)((u + 0x7fffu + ((u >> 16) & 1u)) >> 16);
    } else if (i < 512 * 128 + 128 * 128) {
        int j = i - 512 * 128;
        int k = j >> 7, c = j & 127;
        unsigned u = __builtin_bit_cast(unsigned, W2[j]);
        wt2[c * 128 + k] = (ushort)((u + 0x7fffu + ((u >> 16) & 1u)) >> 16);
    }
}

// ---------------- MFMA GEMM: H = X @ W, + fused hb = bf16(H*dinv) -----------
// Canonical both-in-LDS structure.  A split-bf16 (exact), B bf16-RNE.
// BM=64, BN=128, BK=64; 256 thr = 4 waves; wave = 16 rows x 128 cols.
// A tile: [row 64][slot16 16] f32, phys slot16 = s ^ (row&15)  (conflict-free)
// B tile: [col 128][slot 8 x 16B] bf16, phys slot = s ^ (col&7)
// Both staged via global_load_lds with pre-swizzled COALESCED sources
// (all global reads in the K-loop are contiguous row segments).
// Per iter: [vmcnt(0) (only own stage outstanding); barrier; STAGE(i+1);
//            compute buf[i&1]].  2-buffer, 64 KB LDS -> 2 blocks/CU.
// R13 BUGFIX: A-fragment read uses tile row (wu*16 + lrow), not lrow.
template <int K>
__global__ __launch_bounds__(256) void gemm_mfma_k(const float* __restrict__ X,
                                                   const ushort* __restrict__ wT,
                                                   const float* __restrict__ dinv,
                                                   float* __restrict__ H,
                                                   ushort* __restrict__ hb16,
                                                   int nrows) {
    __shared__ float  lAs[2][64 * 64];     // 2 x 16 KB
    __shared__ ushort lBs[2][128 * 64];    // 2 x 16 KB

    const int tx = threadIdx.x;
    const int wu = __builtin_amdgcn_readfirstlane(tx >> 6);
    const int l = tx & 63;
    const int lrow = l & 15;
    const int kgrp = l >> 4;
    const int rowB = blockIdx.x * 64;             // block row base
    const int row0 = rowB + wu * 16;              // wave row base

    f32x4 acc[8];
#pragma unroll
    for (int g = 0; g < 8; g++) acc[g] = (f32x4){0.f, 0.f, 0.f, 0.f};

    auto STAGE = [&](int buf, int k0) {
        // A: 16 KB, 4 instrs/wave; lane covers (row = j*4 + l/16, slot16 = l&15)
#pragma unroll
        for (int q = 0; q < 4; q++) {
            int j = wu * 4 + q;                   // 0..15
            int row = j * 4 + (l >> 4);           // 0..63
            int slot = l & 15;
            int grow = rowB + row;
            if (grow >= nrows) grow = nrows - 1;  // clamp (stores guarded)
            const float* src = X + (size_t)grow * K + k0 + ((slot ^ (row & 15)) * 4);
            float* dst = &lAs[buf][j * 256];      // +lane*16B by HW
            __builtin_amdgcn_global_load_lds(
                (const __attribute__((address_space(1))) unsigned int*)(const void*)src,
                (__attribute__((address_space(3))) unsigned int*)(void*)dst,
                16, 0, 0);
        }
        // B: 16 KB, 4 instrs/wave; lane covers (col = j*8 + l/8, slot = l&7)
#pragma unroll
        for (int q = 0; q < 4; q++) {
            int j = wu * 4 + q;                   // 0..15
            int col = j * 8 + (l >> 3);           // 0..127
            int slot = l & 7;
            const ushort* src = wT + (size_t)col * K + k0 + ((slot ^ (col & 7)) * 8);
            ushort* dst = &lBs[buf][j * 512];     // +lane*16B by HW
            __builtin_amdgcn_global_load_lds(
                (const __attribute__((address_space(1))) unsigned int*)(const void*)src,
                (__attribute__((address_space(3))) unsigned int*)(void*)dst,
                16, 0, 0);
        }
    };

    constexpr int NIT = K / 64;

    STAGE(0, 0);

#pragma unroll
    for (int i = 0; i < NIT; i++) {
        asm volatile("s_waitcnt vmcnt(0)" ::: "memory");   // own S(i) done
        __builtin_amdgcn_s_barrier();                      // -> all S(i) done
        __builtin_amdgcn_sched_barrier(0);

        if (i + 1 < NIT) STAGE((i + 1) & 1, (i + 1) * 64);
        asm volatile("" ::: "memory");

        const int buf = i & 1;
        const int trow = wu * 16 + lrow;          // this wave's A tile row
#pragma unroll
        for (int ks = 0; ks < 2; ks++) {
            // A fragment: 8 f32 from swizzled LDS, split to bf16 hi/lo (exact)
            int s16 = (ks * 4 + kgrp) * 2;
            f32x4 a0 = *reinterpret_cast<const f32x4*>(
                &lAs[buf][trow * 64 + ((s16 ^ lrow) & 15) * 4]);
            f32x4 a1 = *reinterpret_cast<const f32x4*>(
                &lAs[buf][trow * 64 + (((s16 + 1) ^ lrow) & 15) * 4]);
            short8 ah, al;
#pragma unroll
            for (int j = 0; j < 8; j++) {
                float f = (j < 4) ? a0[j] : a1[j - 4];
                unsigned u = __builtin_bit_cast(unsigned, f);
                ah[j] = (short)(u >> 16);
                float hif = __builtin_bit_cast(float, u & 0xffff0000u);
                float lof = f - hif;
                al[j] = (short)(__builtin_bit_cast(unsigned, lof) >> 16);
            }
#pragma unroll
            for (int g = 0; g < 8; g++) {
                int cc = g * 16 + lrow;
                int phys = (ks * 4 + kgrp) ^ (cc & 7);
                short8 bb = *reinterpret_cast<const short8*>(
                    &lBs[buf][cc * 64 + phys * 8]);
                acc[g] = __builtin_amdgcn_mfma_f32_16x16x32_bf16(ah, bb, acc[g], 0, 0, 0);
                acc[g] = __builtin_amdgcn_mfma_f32_16x16x32_bf16(al, bb, acc[g], 0, 0, 0);
            }
        }
    }

    // C: row = row0 + kgrp*4 + r, col = g*16 + lrow (verified m89 mapping)
#pragma unroll
    for (int r = 0; r < 4; r++) {
        int row = row0 + kgrp * 4 + r;
        if (row < nrows) {
            float dn = dinv[row];
            float* hrow = H + (size_t)row * 128 + lrow;
            ushort* hbrow = hb16 + (size_t)row * 128 + lrow;
#pragma unroll
            for (int g = 0; g < 8; g++) {
                float v = acc[g][r];
                hrow[g * 16] = v;
                unsigned u = __builtin_bit_cast(unsigned, v * dn);
                hbrow[g * 16] = (ushort)((u + 0x7fffu + ((u >> 16) & 1u)) >> 16);
            }
        }
    }
}

// ------ fused aggregate: out[d] = dinv[d]*(h[d]*dinv[d] + sum hb[src]) -------
// then bias + BN(eval) + ReLU.  One 64-lane wave per node, 4 B/lane gathers.
__global__ __launch_bounds__(256) void agg_k(const float* __restrict__ H,
                                             const uint* __restrict__ hb,
                                             const int* __restrict__ rowptr,
                                             const int* __restrict__ esrc,
                                             const float* __restrict__ dinv,
                                             const float* __restrict__ bias,
                                             const float* __restrict__ gamma,
                                             const float* __restrict__ beta,
                                             const float* __restrict__ rm,
                                             const float* __restrict__ rv,
                                             float* __restrict__ OUT,
                                             int nnodes) {
    int node = blockIdx.x * 4 + (threadIdx.x >> 6);
    if (node >= nnodes) return;
    node = __builtin_amdgcn_readfirstlane(node);
    const int l = threadIdx.x & 63;
    const int c = l * 2;
    const float dn = dinv[node];
    const int beg = rowptr[node], end = rowptr[node + 1];

    float2 hv = *reinterpret_cast<const float2*>(H + (size_t)node * 128 + c);
    float ax0 = hv.x * dn, ay0 = hv.y * dn;
    float ax1 = 0.f, ay1 = 0.f, ax2 = 0.f, ay2 = 0.f, ax3 = 0.f, ay3 = 0.f;
    const uint* hbl = hb + l;

    int j = beg;
    for (; j + 3 < end; j += 4) {
        int s0 = esrc[j], s1 = esrc[j + 1], s2 = esrc[j + 2], s3 = esrc[j + 3];
        uint u0 = hbl[(size_t)s0 * 64];
        uint u1 = hbl[(size_t)s1 * 64];
        uint u2 = hbl[(size_t)s2 * 64];
        uint u3 = hbl[(size_t)s3 * 64];
        ax0 += __builtin_bit_cast(float, u0 << 16);
        ay0 += __builtin_bit_cast(float, u0 & 0xffff0000u);
        ax1 += __builtin_bit_cast(float, u1 << 16);
        ay1 += __builtin_bit_cast(float, u1 & 0xffff0000u);
        ax2 += __builtin_bit_cast(float, u2 << 16);
        ay2 += __builtin_bit_cast(float, u2 & 0xffff0000u);
        ax3 += __builtin_bit_cast(float, u3 << 16);
        ay3 += __builtin_bit_cast(float, u3 & 0xffff0000u);
    }
    for (; j < end; j++) {
        uint u0 = hbl[(size_t)esrc[j] * 64];
        ax0 += __builtin_bit_cast(float, u0 << 16);
        ay0 += __builtin_bit_cast(float, u0 & 0xffff0000u);
    }
    float accx = (ax0 + ax1) + (ax2 + ax3);
    float accy = (ay0 + ay1) + (ay2 + ay3);

    float v0 = accx * dn + bias[c];
    float v1 = accy * dn + bias[c + 1];
    v0 = (v0 - rm[c])     * rsqrtf(rv[c] + EPSV)     * gamma[c]     + beta[c];
    v1 = (v1 - rm[c + 1]) * rsqrtf(rv[c + 1] + EPSV) * gamma[c + 1] + beta[c + 1];
    v0 = fmaxf(v0, 0.0f);
    v1 = fmaxf(v1, 0.0f);

    *reinterpret_cast<float2*>(OUT + (size_t)node * 128 + c) = make_float2(v0, v1);
}

// ---------------- mean pool, stage 1: per-(graph, chunk) partial sums --------
__global__ __launch_bounds__(256) void pool1_k(const float* __restrict__ V,
                                               const int* __restrict__ gstart,
                                               float* __restrict__ partial) {
    __shared__ float sh[256];
    const int g = blockIdx.x >> 5;
    const int p = blockIdx.x & 31;
    const int tx = threadIdx.x;
    const int ch = tx & 127;
    const int sub = tx >> 7;
    const int beg = gstart[g], end = gstart[g + 1];
    const int chunk = (end - beg + 31) >> 5;
    const int s = beg + p * chunk;
    const int e = min(s + chunk, end);
    float acc = 0.0f;
    for (int i = s + sub; i < e; i += 2)
        acc += V[(size_t)i * 128 + ch];
    sh[tx] = acc;
    __syncthreads();
    if (tx < 128)
        partial[(size_t)blockIdx.x * 128 + tx] = sh[tx] + sh[tx + 128];
}

// ---------------- mean pool, stage 2 -----------------------------------------
__global__ __launch_bounds__(128) void pool2_k(const float* __restrict__ partial,
                                               const int* __restrict__ gstart,
                                               float* __restrict__ pooled) {
    const int g = blockIdx.x;
    const int ch = threadIdx.x;
    float s = 0.0f;
#pragma unroll
    for (int p = 0; p < 32; p++)
        s += partial[(size_t)((g << 5) + p) * 128 + ch];
    float cnt = fmaxf((float)(gstart[g + 1] - gstart[g]), 1.0f);
    pooled[g * 128 + ch] = s / cnt;
}

// ---------------- final: out[g][o] = pooled[g] @ Wl + bl ---------------------
__global__ __launch_bounds__(128) void final_k(const float* __restrict__ pooled,
                                               const float* __restrict__ Wl,
                                               const float* __restrict__ bl,
                                               float* __restrict__ out) {
    int tx = threadIdx.x;
    int g = tx >> 1, o = tx & 1;
    float s = 0.0f;
#pragma unroll 8
    for (int c = 0; c < 128; c++) s += pooled[g * 128 + c] * Wl[c * 2 + o];
    out[tx] = s + bl[o];
}

extern "C" void kernel_launch(void* const* d_in, const int* in_sizes, int n_in,
                              void* d_out, int out_size, void* d_ws, size_t ws_size,
                              hipStream_t stream) {
    const float* x      = (const float*)d_in[0];
    const int*   ei     = (const int*)d_in[1];
    const int*   batch  = (const int*)d_in[2];
    const float* W1     = (const float*)d_in[3];
    const float* b1     = (const float*)d_in[4];
    const float* gamma1 = (const float*)d_in[5];
    const float* beta1  = (const float*)d_in[6];
    const float* rm1    = (const float*)d_in[7];
    const float* rv1    = (const float*)d_in[8];
    const float* W2     = (const float*)d_in[9];
    const float* b2     = (const float*)d_in[10];
    const float* gamma2 = (const float*)d_in[11];
    const float* beta2  = (const float*)d_in[12];
    const float* rm2    = (const float*)d_in[13];
    const float* rv2    = (const float*)d_in[14];
    const float* Wl     = (const float*)d_in[15];
    const float* bl     = (const float*)d_in[16];
    float* out = (float*)d_out;

    const int nnodes  = in_sizes[2];
    const int nedges  = in_sizes[1] / 2;
    const int ngraphs = 64;
    const int* srcp = ei;
    const int* dstp = ei + nedges;

    float* wsA     = (float*)d_ws;                       // [nnodes*128]
    float* wsB     = wsA + (size_t)nnodes * 128;         // [nnodes*128]
    float* dinv    = wsB + (size_t)nnodes * 128;         // [nnodes]
    float* pooled  = dinv + nnodes;                      // [64*128]
    float* partial = pooled + 64 * 128;                  // [64*32*128]
    int*   cnt     = (int*)(partial + 64 * 32 * 128);    // [nnodes]
    int*   rowptr  = cnt + nnodes;                       // [nnodes+1]
    int*   cur     = rowptr + nnodes + 1;                // [nnodes]
    int*   bsum    = cur + nnodes;                       // [64]
    int*   gstart  = bsum + 64;                          // [65]
    int*   esrc    = gstart + 65;                        // [nedges]
    uintptr_t wp   = ((uintptr_t)(esrc + nedges) + 15) & ~(uintptr_t)15;
    ushort* wt1  = (ushort*)wp;                          // [128*512]
    ushort* wt2  = wt1 + 512 * 128;                      // [128*128]
    ushort* hb16 = wt2 + 128 * 128;                      // [nnodes*128] bf16
    uint*   hb   = (uint*)hb16;                          // same buffer, uint view

    dim3 blk(256);
    const int gNodes = (nnodes + 255) / 256;
    const int gEdges = (nedges + 255) / 256;
    const int gGemm  = (nnodes + 63) / 64;
    const int gAgg   = (nnodes + 3) / 4;
    const int nScanB = (nnodes + 1023) / 1024;

    // ---- graph preprocessing (CSR by dst + graph segments + W prep) ----
    init_k<<<gNodes, blk, 0, stream>>>(cnt, batch, gstart, nnodes, ngraphs);
    wprep_k<<<(512 * 128 + 128 * 128 + 255) / 256, blk, 0, stream>>>(W1, W2, wt1, wt2);
    degcount_k<<<gEdges, blk, 0, stream>>>(dstp, cnt, nedges);
    scan1_k<<<nScanB, blk, 0, stream>>>(cnt, rowptr, bsum, dinv, nnodes);
    scan2_k<<<1, 64, 0, stream>>>(bsum, nScanB);
    scan3_k<<<nScanB, blk, 0, stream>>>(rowptr, cur, bsum, nnodes, nedges);
    fill_k<<<gEdges, blk, 0, stream>>>(srcp, dstp, cur, esrc, nedges);

    // ---- layer 1: MFMA GEMM (+hb) + fused aggregate/BN/ReLU ----
    gemm_mfma_k<512><<<gGemm, blk, 0, stream>>>(x, wt1, dinv, wsA, hb16, nnodes);
    agg_k<<<gAgg, blk, 0, stream>>>(wsA, hb, rowptr, esrc, dinv, b1, gamma1, beta1,
                                    rm1, rv1, wsB, nnodes);

    // ---- layer 2: MFMA GEMM (+hb) + fused aggregate/BN/ReLU ----
    gemm_mfma_k<128><<<gGemm, blk, 0, stream>>>(wsB, wt2, dinv, wsA, hb16, nnodes);
    agg_k<<<gAgg, blk, 0, stream>>>(wsA, hb, rowptr, esrc, dinv, b2, gamma2, beta2,
                                    rm2, rv2, wsB, nnodes);

    // ---- readout ----
    pool1_k<<<ngraphs * 32, blk, 0, stream>>>(wsB, gstart, partial);
    pool2_k<<<ngraphs, 128, 0, stream>>>(partial, gstart, pooled);
    final_k<<<1, 128, 0, stream>>>(pooled, Wl, bl, out);
}

// Round 15
// 233.487 us; speedup vs baseline: 1.1803x; 1.1070x over previous
//
#include <hip/hip_runtime.h>

#define EPSV 1e-5f

typedef __attribute__((ext_vector_type(8))) short short8;
typedef __attribute__((ext_vector_type(4))) float f32x4;
typedef unsigned int uint;
typedef unsigned short ushort;

// ------- init: cnt=0, W1/W2 transpose+bf16-RNE, graph starts (block 0) -------
__global__ __launch_bounds__(256) void init_k(int* __restrict__ cnt,
                                              const int* __restrict__ batch,
                                              int* __restrict__ gstart,
                                              const float* __restrict__ W1,
                                              const float* __restrict__ W2,
                                              ushort* __restrict__ wt1,
                                              ushort* __restrict__ wt2,
                                              int nnodes, int ngraphs) {
    int i = blockIdx.x * 256 + threadIdx.x;
    if (i < nnodes) cnt[i] = 0;
    if (i < 512 * 128) {
        int k = i >> 7, c = i & 127;
        unsigned u = __builtin_bit_cast(unsigned, W1[i]);
        wt1[c * 512 + k] = (ushort)((u + 0x7fffu + ((u >> 16) & 1u)) >> 16);
    } else if (i < 512 * 128 + 128 * 128) {
        int j = i - 512 * 128;
        int k = j >> 7, c = j & 127;
        unsigned u = __builtin_bit_cast(unsigned, W2[j]);
        wt2[c * 128 + k] = (ushort)((u + 0x7fffu + ((u >> 16) & 1u)) >> 16);
    }
    if (blockIdx.x == 0 && threadIdx.x <= ngraphs) {
        int g = threadIdx.x;
        int lo = 0, hi = nnodes;
        while (lo < hi) {
            int mid = (lo + hi) >> 1;
            if (batch[mid] < g) lo = mid + 1; else hi = mid;
        }
        gstart[g] = lo;
    }
}

__global__ __launch_bounds__(256) void degcount_k(const int* __restrict__ dst,
                                                  int* __restrict__ cnt,
                                                  int nedges) {
    int i = blockIdx.x * 256 + threadIdx.x;
    if (i < nedges) atomicAdd(&cnt[dst[i]], 1);
}

// ---------------- exclusive scan of cnt[] -> rowptr[] (+ dinv) ---------------
__global__ __launch_bounds__(256) void scan1_k(const int* __restrict__ cnt,
                                               int* __restrict__ rowptr,
                                               int* __restrict__ bsum,
                                               float* __restrict__ dinv, int n) {
    __shared__ int sh[256];
    const int tx = threadIdx.x;
    const int base = blockIdx.x * 1024;
    int v[4];
    int s = 0;
#pragma unroll
    for (int j = 0; j < 4; j++) {
        int idx = base + tx * 4 + j;
        v[j] = (idx < n) ? cnt[idx] : 0;
        if (idx < n) dinv[idx] = rsqrtf(1.0f + (float)v[j]);
        s += v[j];
    }
    sh[tx] = s;
    __syncthreads();
#pragma unroll
    for (int off = 1; off < 256; off <<= 1) {
        int t = (tx >= off) ? sh[tx - off] : 0;
        __syncthreads();
        sh[tx] += t;
        __syncthreads();
    }
    int run = sh[tx] - s;
#pragma unroll
    for (int j = 0; j < 4; j++) {
        int idx = base + tx * 4 + j;
        if (idx < n) rowptr[idx] = run;
        run += v[j];
    }
    if (tx == 255) bsum[blockIdx.x] = sh[255];
}

__global__ __launch_bounds__(64) void scan2_k(int* __restrict__ bsum, int nb) {
    __shared__ int sh[64];
    const int tx = threadIdx.x;
    int v = (tx < nb) ? bsum[tx] : 0;
    sh[tx] = v;
    __syncthreads();
#pragma unroll
    for (int off = 1; off < 64; off <<= 1) {
        int t = (tx >= off) ? sh[tx - off] : 0;
        __syncthreads();
        sh[tx] += t;
        __syncthreads();
    }
    if (tx < nb) bsum[tx] = sh[tx] - v;
}

__global__ __launch_bounds__(256) void scan3_k(int* __restrict__ rowptr,
                                               int* __restrict__ cur,
                                               const int* __restrict__ bsum,
                                               int n, int nedges) {
    const int tx = threadIdx.x;
    const int base = blockIdx.x * 1024;
    int off = bsum[blockIdx.x];
#pragma unroll
    for (int j = 0; j < 4; j++) {
        int idx = base + tx * 4 + j;
        if (idx < n) {
            int r = rowptr[idx] + off;
            rowptr[idx] = r;
            cur[idx] = r;
        }
    }
    if (blockIdx.x == 0 && tx == 0) rowptr[n] = nedges;
}

__global__ __launch_bounds__(256) void fill_k(const int* __restrict__ src,
                                              const int* __restrict__ dst,
                                              int* __restrict__ cur,
                                              int* __restrict__ esrc, int nedges) {
    int i = blockIdx.x * 256 + threadIdx.x;
    if (i >= nedges) return;
    int pos = atomicAdd(&cur[dst[i]], 1);
    esrc[pos] = src[i];
}

// ---------------- MFMA GEMM: hb = bf16_rne((X @ W) * dinv) -------------------
// Canonical both-in-LDS structure (round-14, verified).  A split-bf16 (exact),
// B bf16-RNE.  BM=64, BN=128, BK=64; 256 thr = 4 waves; wave = 16r x 128c.
// A tile: [row 64][slot16 16] f32, phys slot16 = s ^ (row&15)
// B tile: [col 128][slot 8 x 16B] bf16, phys slot = s ^ (col&7)
// Epilogue writes ONLY hb (bf16 of H*dinv) — no f32 H materialization.
template <int K>
__global__ __launch_bounds__(256) void gemm_mfma_k(const float* __restrict__ X,
                                                   const ushort* __restrict__ wT,
                                                   const float* __restrict__ dinv,
                                                   ushort* __restrict__ hb16,
                                                   int nrows) {
    __shared__ float  lAs[2][64 * 64];     // 2 x 16 KB
    __shared__ ushort lBs[2][128 * 64];    // 2 x 16 KB

    const int tx = threadIdx.x;
    const int wu = __builtin_amdgcn_readfirstlane(tx >> 6);
    const int l = tx & 63;
    const int lrow = l & 15;
    const int kgrp = l >> 4;
    const int rowB = blockIdx.x * 64;             // block row base
    const int row0 = rowB + wu * 16;              // wave row base

    f32x4 acc[8];
#pragma unroll
    for (int g = 0; g < 8; g++) acc[g] = (f32x4){0.f, 0.f, 0.f, 0.f};

    auto STAGE = [&](int buf, int k0) {
#pragma unroll
        for (int q = 0; q < 4; q++) {
            int j = wu * 4 + q;                   // 0..15
            int row = j * 4 + (l >> 4);           // 0..63
            int slot = l & 15;
            int grow = rowB + row;
            if (grow >= nrows) grow = nrows - 1;  // clamp (stores guarded)
            const float* src = X + (size_t)grow * K + k0 + ((slot ^ (row & 15)) * 4);
            float* dst = &lAs[buf][j * 256];      // +lane*16B by HW
            __builtin_amdgcn_global_load_lds(
                (const __attribute__((address_space(1))) unsigned int*)(const void*)src,
                (__attribute__((address_space(3))) unsigned int*)(void*)dst,
                16, 0, 0);
        }
#pragma unroll
        for (int q = 0; q < 4; q++) {
            int j = wu * 4 + q;                   // 0..15
            int col = j * 8 + (l >> 3);           // 0..127
            int slot = l & 7;
            const ushort* src = wT + (size_t)col * K + k0 + ((slot ^ (col & 7)) * 8);
            ushort* dst = &lBs[buf][j * 512];     // +lane*16B by HW
            __builtin_amdgcn_global_load_lds(
                (const __attribute__((address_space(1))) unsigned int*)(const void*)src,
                (__attribute__((address_space(3))) unsigned int*)(void*)dst,
                16, 0, 0);
        }
    };

    constexpr int NIT = K / 64;

    STAGE(0, 0);

#pragma unroll
    for (int i = 0; i < NIT; i++) {
        asm volatile("s_waitcnt vmcnt(0)" ::: "memory");   // own S(i) done
        __builtin_amdgcn_s_barrier();                      // -> all S(i) done
        __builtin_amdgcn_sched_barrier(0);

        if (i + 1 < NIT) STAGE((i + 1) & 1, (i + 1) * 64);
        asm volatile("" ::: "memory");

        const int buf = i & 1;
        const int trow = wu * 16 + lrow;          // this wave's A tile row
#pragma unroll
        for (int ks = 0; ks < 2; ks++) {
            int s16 = (ks * 4 + kgrp) * 2;
            f32x4 a0 = *reinterpret_cast<const f32x4*>(
                &lAs[buf][trow * 64 + ((s16 ^ lrow) & 15) * 4]);
            f32x4 a1 = *reinterpret_cast<const f32x4*>(
                &lAs[buf][trow * 64 + (((s16 + 1) ^ lrow) & 15) * 4]);
            short8 ah, al;
#pragma unroll
            for (int j = 0; j < 8; j++) {
                float f = (j < 4) ? a0[j] : a1[j - 4];
                unsigned u = __builtin_bit_cast(unsigned, f);
                ah[j] = (short)(u >> 16);
                float hif = __builtin_bit_cast(float, u & 0xffff0000u);
                float lof = f - hif;
                al[j] = (short)(__builtin_bit_cast(unsigned, lof) >> 16);
            }
#pragma unroll
            for (int g = 0; g < 8; g++) {
                int cc = g * 16 + lrow;
                int phys = (ks * 4 + kgrp) ^ (cc & 7);
                short8 bb = *reinterpret_cast<const short8*>(
                    &lBs[buf][cc * 64 + phys * 8]);
                acc[g] = __builtin_amdgcn_mfma_f32_16x16x32_bf16(ah, bb, acc[g], 0, 0, 0);
                acc[g] = __builtin_amdgcn_mfma_f32_16x16x32_bf16(al, bb, acc[g], 0, 0, 0);
            }
        }
    }

    // C: row = row0 + kgrp*4 + r, col = g*16 + lrow (verified m89 mapping)
#pragma unroll
    for (int r = 0; r < 4; r++) {
        int row = row0 + kgrp * 4 + r;
        if (row < nrows) {
            float dn = dinv[row];
            ushort* hbrow = hb16 + (size_t)row * 128 + lrow;
#pragma unroll
            for (int g = 0; g < 8; g++) {
                unsigned u = __builtin_bit_cast(unsigned, acc[g][r] * dn);
                hbrow[g * 16] = (ushort)((u + 0x7fffu + ((u >> 16) & 1u)) >> 16);
            }
        }
    }
}

// ------ fused aggregate: out[d] = dinv[d]*(hb[d] + sum hb[src]) --------------
// then bias + BN(eval) + ReLU.  One 64-lane wave per node; self term uses
// hb[d] = bf16(h*dinv) directly (one extra rounding on 1 of ~17 terms).
// 8 gathers in flight (MLP 8).
__global__ __launch_bounds__(256) void agg_k(const uint* __restrict__ hb,
                                             const int* __restrict__ rowptr,
                                             const int* __restrict__ esrc,
                                             const float* __restrict__ dinv,
                                             const float* __restrict__ bias,
                                             const float* __restrict__ gamma,
                                             const float* __restrict__ beta,
                                             const float* __restrict__ rm,
                                             const float* __restrict__ rv,
                                             float* __restrict__ OUT,
                                             int nnodes) {
    int node = blockIdx.x * 4 + (threadIdx.x >> 6);
    if (node >= nnodes) return;
    node = __builtin_amdgcn_readfirstlane(node);
    const int l = threadIdx.x & 63;
    const int c = l * 2;
    const float dn = dinv[node];
    const int beg = rowptr[node], end = rowptr[node + 1];
    const uint* hbl = hb + l;

    uint us = hbl[(size_t)node * 64];             // self-loop term
    float ax0 = __builtin_bit_cast(float, us << 16);
    float ay0 = __builtin_bit_cast(float, us & 0xffff0000u);
    float ax1 = 0.f, ay1 = 0.f, ax2 = 0.f, ay2 = 0.f, ax3 = 0.f, ay3 = 0.f;

    int j = beg;
    for (; j + 7 < end; j += 8) {
        int s0 = esrc[j],     s1 = esrc[j + 1], s2 = esrc[j + 2], s3 = esrc[j + 3];
        int s4 = esrc[j + 4], s5 = esrc[j + 5], s6 = esrc[j + 6], s7 = esrc[j + 7];
        uint u0 = hbl[(size_t)s0 * 64];
        uint u1 = hbl[(size_t)s1 * 64];
        uint u2 = hbl[(size_t)s2 * 64];
        uint u3 = hbl[(size_t)s3 * 64];
        uint u4 = hbl[(size_t)s4 * 64];
        uint u5 = hbl[(size_t)s5 * 64];
        uint u6 = hbl[(size_t)s6 * 64];
        uint u7 = hbl[(size_t)s7 * 64];
        ax0 += __builtin_bit_cast(float, u0 << 16);
        ay0 += __builtin_bit_cast(float, u0 & 0xffff0000u);
        ax1 += __builtin_bit_cast(float, u1 << 16);
        ay1 += __builtin_bit_cast(float, u1 & 0xffff0000u);
        ax2 += __builtin_bit_cast(float, u2 << 16);
        ay2 += __builtin_bit_cast(float, u2 & 0xffff0000u);
        ax3 += __builtin_bit_cast(float, u3 << 16);
        ay3 += __builtin_bit_cast(float, u3 & 0xffff0000u);
        ax0 += __builtin_bit_cast(float, u4 << 16);
        ay0 += __builtin_bit_cast(float, u4 & 0xffff0000u);
        ax1 += __builtin_bit_cast(float, u5 << 16);
        ay1 += __builtin_bit_cast(float, u5 & 0xffff0000u);
        ax2 += __builtin_bit_cast(float, u6 << 16);
        ay2 += __builtin_bit_cast(float, u6 & 0xffff0000u);
        ax3 += __builtin_bit_cast(float, u7 << 16);
        ay3 += __builtin_bit_cast(float, u7 & 0xffff0000u);
    }
    for (; j + 1 < end; j += 2) {
        int s0 = esrc[j], s1 = esrc[j + 1];
        uint u0 = hbl[(size_t)s0 * 64];
        uint u1 = hbl[(size_t)s1 * 64];
        ax0 += __builtin_bit_cast(float, u0 << 16);
        ay0 += __builtin_bit_cast(float, u0 & 0xffff0000u);
        ax1 += __builtin_bit_cast(float, u1 << 16);
        ay1 += __builtin_bit_cast(float, u1 & 0xffff0000u);
    }
    if (j < end) {
        uint u0 = hbl[(size_t)esrc[j] * 64];
        ax0 += __builtin_bit_cast(float, u0 << 16);
        ay0 += __builtin_bit_cast(float, u0 & 0xffff0000u);
    }
    float accx = (ax0 + ax1) + (ax2 + ax3);
    float accy = (ay0 + ay1) + (ay2 + ay3);

    float v0 = accx * dn + bias[c];
    float v1 = accy * dn + bias[c + 1];
    v0 = (v0 - rm[c])     * rsqrtf(rv[c] + EPSV)     * gamma[c]     + beta[c];
    v1 = (v1 - rm[c + 1]) * rsqrtf(rv[c + 1] + EPSV) * gamma[c + 1] + beta[c + 1];
    v0 = fmaxf(v0, 0.0f);
    v1 = fmaxf(v1, 0.0f);

    *reinterpret_cast<float2*>(OUT + (size_t)node * 128 + c) = make_float2(v0, v1);
}

// ---------------- mean pool, stage 1: per-(graph, chunk) partial sums --------
__global__ __launch_bounds__(256) void pool1_k(const float* __restrict__ V,
                                               const int* __restrict__ gstart,
                                               float* __restrict__ partial) {
    __shared__ float sh[256];
    const int g = blockIdx.x >> 5;
    const int p = blockIdx.x & 31;
    const int tx = threadIdx.x;
    const int ch = tx & 127;
    const int sub = tx >> 7;
    const int beg = gstart[g], end = gstart[g + 1];
    const int chunk = (end - beg + 31) >> 5;
    const int s = beg + p * chunk;
    const int e = min(s + chunk, end);
    float acc = 0.0f;
    for (int i = s + sub; i < e; i += 2)
        acc += V[(size_t)i * 128 + ch];
    sh[tx] = acc;
    __syncthreads();
    if (tx < 128)
        partial[(size_t)blockIdx.x * 128 + tx] = sh[tx] + sh[tx + 128];
}

// -------- mean pool stage 2 + final linear: out[g][:] (fused) ----------------
__global__ __launch_bounds__(128) void pool2_k(const float* __restrict__ partial,
                                               const int* __restrict__ gstart,
                                               const float* __restrict__ Wl,
                                               const float* __restrict__ bl,
                                               float* __restrict__ out) {
    __shared__ float s0[128], s1[128];
    const int g = blockIdx.x;
    const int ch = threadIdx.x;
    float s = 0.0f;
#pragma unroll
    for (int p = 0; p < 32; p++)
        s += partial[(size_t)((g << 5) + p) * 128 + ch];
    float cnt = fmaxf((float)(gstart[g + 1] - gstart[g]), 1.0f);
    float pooled = s / cnt;
    s0[ch] = pooled * Wl[ch * 2];
    s1[ch] = pooled * Wl[ch * 2 + 1];
    __syncthreads();
#pragma unroll
    for (int off = 64; off > 0; off >>= 1) {
        if (ch < off) { s0[ch] += s0[ch + off]; s1[ch] += s1[ch + off]; }
        __syncthreads();
    }
    if (ch == 0) {
        out[g * 2]     = s0[0] + bl[0];
        out[g * 2 + 1] = s1[0] + bl[1];
    }
}

extern "C" void kernel_launch(void* const* d_in, const int* in_sizes, int n_in,
                              void* d_out, int out_size, void* d_ws, size_t ws_size,
                              hipStream_t stream) {
    const float* x      = (const float*)d_in[0];
    const int*   ei     = (const int*)d_in[1];
    const int*   batch  = (const int*)d_in[2];
    const float* W1     = (const float*)d_in[3];
    const float* b1     = (const float*)d_in[4];
    const float* gamma1 = (const float*)d_in[5];
    const float* beta1  = (const float*)d_in[6];
    const float* rm1    = (const float*)d_in[7];
    const float* rv1    = (const float*)d_in[8];
    const float* W2     = (const float*)d_in[9];
    const float* b2     = (const float*)d_in[10];
    const float* gamma2 = (const float*)d_in[11];
    const float* beta2  = (const float*)d_in[12];
    const float* rm2    = (const float*)d_in[13];
    const float* rv2    = (const float*)d_in[14];
    const float* Wl     = (const float*)d_in[15];
    const float* bl     = (const float*)d_in[16];
    float* out = (float*)d_out;

    const int nnodes  = in_sizes[2];
    const int nedges  = in_sizes[1] / 2;
    const int ngraphs = 64;
    const int* srcp = ei;
    const int* dstp = ei + nedges;

    float* wsB     = (float*)d_ws;                       // [nnodes*128]
    float* dinv    = wsB + (size_t)nnodes * 128;         // [nnodes]
    float* partial = dinv + nnodes;                      // [64*32*128]
    int*   cnt     = (int*)(partial + 64 * 32 * 128);    // [nnodes]
    int*   rowptr  = cnt + nnodes;                       // [nnodes+1]
    int*   cur     = rowptr + nnodes + 1;                // [nnodes]
    int*   bsum    = cur + nnodes;                       // [64]
    int*   gstart  = bsum + 64;                          // [65]
    int*   esrc    = gstart + 65;                        // [nedges]
    uintptr_t wp   = ((uintptr_t)(esrc + nedges) + 15) & ~(uintptr_t)15;
    ushort* wt1  = (ushort*)wp;                          // [128*512]
    ushort* wt2  = wt1 + 512 * 128;                      // [128*128]
    ushort* hb16 = wt2 + 128 * 128;                      // [nnodes*128] bf16
    uint*   hb   = (uint*)hb16;                          // same buffer, uint view

    dim3 blk(256);
    const int gNodes = (nnodes + 255) / 256;
    const int gEdges = (nedges + 255) / 256;
    const int gGemm  = (nnodes + 63) / 64;
    const int gAgg   = (nnodes + 3) / 4;
    const int nScanB = (nnodes + 1023) / 1024;
    const int gInit  = max(gNodes, (512 * 128 + 128 * 128 + 255) / 256);

    // ---- graph preprocessing (CSR by dst + graph segments + W prep) ----
    init_k<<<gInit, blk, 0, stream>>>(cnt, batch, gstart, W1, W2, wt1, wt2,
                                      nnodes, ngraphs);
    degcount_k<<<gEdges, blk, 0, stream>>>(dstp, cnt, nedges);
    scan1_k<<<nScanB, blk, 0, stream>>>(cnt, rowptr, bsum, dinv, nnodes);
    scan2_k<<<1, 64, 0, stream>>>(bsum, nScanB);
    scan3_k<<<nScanB, blk, 0, stream>>>(rowptr, cur, bsum, nnodes, nedges);
    fill_k<<<gEdges, blk, 0, stream>>>(srcp, dstp, cur, esrc, nedges);

    // ---- layer 1: MFMA GEMM (hb only) + fused aggregate/BN/ReLU ----
    gemm_mfma_k<512><<<gGemm, blk, 0, stream>>>(x, wt1, dinv, hb16, nnodes);
    agg_k<<<gAgg, blk, 0, stream>>>(hb, rowptr, esrc, dinv, b1, gamma1, beta1,
                                    rm1, rv1, wsB, nnodes);

    // ---- layer 2: MFMA GEMM (hb only) + fused aggregate/BN/ReLU ----
    gemm_mfma_k<128><<<gGemm, blk, 0, stream>>>(wsB, wt2, dinv, hb16, nnodes);
    agg_k<<<gAgg, blk, 0, stream>>>(hb, rowptr, esrc, dinv, b2, gamma2, beta2,
                                    rm2, rv2, wsB, nnodes);

    // ---- readout ----
    pool1_k<<<ngraphs * 32, blk, 0, stream>>>(wsB, gstart, partial);
    pool2_k<<<ngraphs, 128, 0, stream>>>(partial, gstart, Wl, bl, out);
}